// Round 15
// baseline (241.420 us; speedup 1.0000x reference)
//
#include <hip/hip_runtime.h>
#include <hip/hip_bf16.h>

#define N_NODES 4096
#define DIM 256
#define NHEAD 4
#define NEDGE 131072
#define MWORDS 128           // 4096 bits / 32 per mask row
#define MAXDEG 192           // mean deg ~65 (Poisson); 192 is >15 sigma
#define GBK 64               // GEMM K-step
#define MASK_BLOCKS 528      // (NEDGE + N_NODES) / 256
#define CONV_BLOCKS 1792     // (x 1048576 + Wq/Wk/Wv 3*262144) / 1024
#define PREP_BLOCKS 64       // 16 f-tiles x 4 heads

typedef unsigned short ushort_t;
typedef __attribute__((ext_vector_type(8))) short short8;
typedef __attribute__((ext_vector_type(4))) float f32x4;

__device__ __forceinline__ ushort_t f2bf(float f) {
    unsigned u = __float_as_uint(f);
    unsigned r = u + 0x7FFFu + ((u >> 16) & 1u);   // round-to-nearest-even
    return (ushort_t)(r >> 16);
}
__device__ __forceinline__ float bf2f(ushort_t u) {
    return __uint_as_float((unsigned)u << 16);
}

// async global->LDS, 16B per lane; dest = wave-uniform base + lane*16 (linear)
#define GLD16(g, l) __builtin_amdgcn_global_load_lds( \
    (__attribute__((address_space(1))) void*)(g),     \
    (__attribute__((address_space(3))) void*)(l), 16, 0, 0)

// ---------------------------------------------------------------- init: mask + converts + weight-merge prep
// blocks [0,528): mask build. [528,2320): fp32->bf16 converts (x,Wq,Wk,Wv).
// [2320,2384): prep: Mstack[f][h*256+e] = sum_d Wp[f][h*256+d]*Wo[h][d][e] (bf16),
//              bcomb[f] = bp[f] + sum_{h,d} Wp[f][h*256+d]*bo[h][d] (atomicAdd, zeroed).
__global__ __launch_bounds__(256) void init_kernel(
    const int* __restrict__ ei, unsigned* __restrict__ mask,
    const float* __restrict__ x,  const float* __restrict__ Wq,
    const float* __restrict__ Wk, const float* __restrict__ Wv,
    const float* __restrict__ Wo, const float* __restrict__ Wp,
    const float* __restrict__ bo, const float* __restrict__ bp,
    ushort_t* __restrict__ xb, ushort_t* __restrict__ wstack,
    ushort_t* __restrict__ mstack, float* __restrict__ bcomb) {
    const int bid = blockIdx.x;
    if (bid < MASK_BLOCKS) {
        const int t = bid * 256 + threadIdx.x;
        if (t < NEDGE) {
            const int r = ei[t] & (N_NODES - 1);
            const int c = ei[NEDGE + t] & (N_NODES - 1);
            atomicOr(&mask[r * MWORDS + (c >> 5)], 1u << (c & 31));
            atomicOr(&mask[c * MWORDS + (r >> 5)], 1u << (r & 31));
        } else if (t < NEDGE + N_NODES) {
            const int i = t - NEDGE;
            atomicOr(&mask[i * MWORDS + (i >> 5)], 1u << (i & 31));
        }
        return;
    }
    if (bid < MASK_BLOCKS + CONV_BLOCKS) {
        const int e = ((bid - MASK_BLOCKS) * 256 + threadIdx.x) << 2;
        const float* src; ushort_t* dst; int off;
        if (e < 1048576)      { src = x;  dst = xb;              off = e; }
        else if (e < 1310720) { src = Wq; dst = wstack;          off = e - 1048576; }
        else if (e < 1572864) { src = Wk; dst = wstack + 262144; off = e - 1310720; }
        else                  { src = Wv; dst = wstack + 524288; off = e - 1572864; }
        const float4 v = *(const float4*)(src + off);
        ushort4 r;
        r.x = f2bf(v.x); r.y = f2bf(v.y); r.z = f2bf(v.z); r.w = f2bf(v.w);
        *(ushort4*)(dst + off) = r;
        return;
    }
    // ---- prep
    const int pb = bid - (MASK_BLOCKS + CONV_BLOCKS);
    const int h = pb & 3;
    const int f0 = (pb >> 2) << 4;       // 16 consecutive f rows
    const int e = threadIdx.x;
    const float* woh = Wo + (size_t)h * (DIM * DIM);
    float acc[16];
#pragma unroll
    for (int f = 0; f < 16; ++f) acc[f] = 0.f;
    for (int d = 0; d < 256; ++d) {
        const float wv = woh[d * 256 + e];        // coalesced across e
#pragma unroll
        for (int f = 0; f < 16; ++f)
            acc[f] += Wp[(size_t)(f0 + f) * 1024 + (h << 8) + d] * wv;   // uniform s-loads
    }
#pragma unroll
    for (int f = 0; f < 16; ++f)
        mstack[(size_t)(f0 + f) * 1024 + (h << 8) + e] = f2bf(acc[f]);
    if (e < 16) {
        float s = (h == 0) ? bp[f0 + e] : 0.f;
        for (int d = 0; d < 256; ++d)
            s += Wp[(size_t)(f0 + e) * 1024 + (h << 8) + d] * bo[(h << 8) + d];
        atomicAdd(&bcomb[f0 + e], s);
    }
}

// ---------------------------------------------------------------- QKV MFMA GEMM (global_load_lds staging)
// D[ch][node] = sum_k Wb[ch][k]*Xb[node][k] + bias; 128x128 tile, 4 waves, K=256.
// q -> qb bf16 [h][node][256]; k,v -> kvh [h][node][k256|v256].
__global__ __launch_bounds__(256) void qkv_gemm_kernel(
    const ushort_t* __restrict__ Wb, const ushort_t* __restrict__ Xb,
    const float* __restrict__ bq, const float* __restrict__ bk,
    const float* __restrict__ bv,
    ushort_t* __restrict__ qb, ushort_t* __restrict__ kvh) {
    __shared__ ushort_t Wt[128][GBK];
    __shared__ ushort_t Xt[128][GBK];
    const int tid = threadIdx.x;
    const int lane = tid & 63;
    const int wid = tid >> 6;
    const int wr = wid >> 1, wc = wid & 1;
    const int chB = blockIdx.x * 128;
    const int ndB = blockIdx.y * 128;
    const int K = 256;

    f32x4 acc[4][4] = {};

    for (int kt = 0; kt < K; kt += GBK) {
        __syncthreads();   // prior compute done; safe to overwrite LDS
#pragma unroll
        for (int c = 0; c < 4; ++c) {
            const int r0 = (wid << 5) + (c << 3);       // wave's 8-row chunk
            GLD16(Wb + (size_t)(chB + r0 + (lane >> 3)) * K + kt + ((lane & 7) << 3),
                  &Wt[r0][0]);
            GLD16(Xb + (size_t)(ndB + r0 + (lane >> 3)) * K + kt + ((lane & 7) << 3),
                  &Xt[r0][0]);
        }
        __syncthreads();   // vmcnt drained by all waves -> LDS tile complete
#pragma unroll
        for (int kk = 0; kk < 2; ++kk) {
            short8 af[4], bf[4];
            const int ko = (kk << 5) + ((lane >> 4) << 3);
#pragma unroll
            for (int m = 0; m < 4; ++m)
                af[m] = *(const short8*)&Wt[wr * 64 + m * 16 + (lane & 15)][ko];
#pragma unroll
            for (int n = 0; n < 4; ++n)
                bf[n] = *(const short8*)&Xt[wc * 64 + n * 16 + (lane & 15)][ko];
#pragma unroll
            for (int m = 0; m < 4; ++m)
#pragma unroll
                for (int n = 0; n < 4; ++n)
                    acc[m][n] = __builtin_amdgcn_mfma_f32_16x16x32_bf16(
                        af[m], bf[n], acc[m][n], 0, 0, 0);
        }
    }

    const int lhi = lane >> 4;
    const int llo = lane & 15;
    const int op = chB >> 10;
    const int h = (chB >> 8) & 3;
#pragma unroll
    for (int m = 0; m < 4; ++m) {
        const int ch = chB + wr * 64 + m * 16 + (lhi << 2);
        const float* bb = (op == 0 ? bq : op == 1 ? bk : bv) + (h << 8);
        const float4 bia = *(const float4*)&bb[ch & 255];
#pragma unroll
        for (int n = 0; n < 4; ++n) {
            const int node = ndB + wc * 64 + n * 16 + llo;
            ushort4 r;
            r.x = f2bf(acc[m][n][0] + bia.x);
            r.y = f2bf(acc[m][n][1] + bia.y);
            r.z = f2bf(acc[m][n][2] + bia.z);
            r.w = f2bf(acc[m][n][3] + bia.w);
            const int c = ch & 255;
            if (op == 0)
                *(ushort4*)&qb[(((size_t)h * N_NODES + node) << 8) + c] = r;
            else if (op == 1)
                *(ushort4*)&kvh[(((size_t)h * N_NODES + node) << 9) + c] = r;
            else
                *(ushort4*)&kvh[(((size_t)h * N_NODES + node) << 9) + 256 + c] = r;
        }
    }
}

// ---------------------------------------------------------------- merged projection + LayerNorm
// out[node][f] = LN( sum_k ob[node][k]*Mstack[f][k] + bcomb[f] ) * gamma + beta
// K=1024 (o heads stacked); 256f x 64 nodes per block; global_load_lds staging.
__global__ __launch_bounds__(256) void final_ln_kernel(
    const ushort_t* __restrict__ Wb,      // mstack [256][1024]
    const ushort_t* __restrict__ Xb,      // ob [4096][1024] node-major
    const float* __restrict__ bcomb,
    const float* __restrict__ gamma, const float* __restrict__ beta,
    float* __restrict__ out) {
    __shared__ ushort_t Wt[256][GBK];
    __shared__ ushort_t Xt[64][GBK];
    __shared__ float redS[4][64];
    __shared__ float redQ[4][64];
    const int tid = threadIdx.x;
    const int lane = tid & 63;
    const int wid = tid >> 6;
    const int ndB = blockIdx.x * 64;

    f32x4 acc[4][4] = {};

    for (int kt = 0; kt < 1024; kt += GBK) {
        __syncthreads();
#pragma unroll
        for (int c = 0; c < 8; ++c) {
            const int r0 = (wid << 6) + (c << 3);
            GLD16(Wb + (size_t)(r0 + (lane >> 3)) * 1024 + kt + ((lane & 7) << 3),
                  &Wt[r0][0]);
        }
#pragma unroll
        for (int c = 0; c < 2; ++c) {
            const int r0 = (wid << 4) + (c << 3);
            GLD16(Xb + (size_t)(ndB + r0 + (lane >> 3)) * 1024 + kt + ((lane & 7) << 3),
                  &Xt[r0][0]);
        }
        __syncthreads();
#pragma unroll
        for (int kk = 0; kk < 2; ++kk) {
            short8 af[4], bf[4];
            const int ko = (kk << 5) + ((lane >> 4) << 3);
#pragma unroll
            for (int m = 0; m < 4; ++m)
                af[m] = *(const short8*)&Wt[wid * 64 + m * 16 + (lane & 15)][ko];
#pragma unroll
            for (int n = 0; n < 4; ++n)
                bf[n] = *(const short8*)&Xt[n * 16 + (lane & 15)][ko];
#pragma unroll
            for (int m = 0; m < 4; ++m)
#pragma unroll
                for (int n = 0; n < 4; ++n)
                    acc[m][n] = __builtin_amdgcn_mfma_f32_16x16x32_bf16(
                        af[m], bf[n], acc[m][n], 0, 0, 0);
        }
    }

    const int lhi = lane >> 4;
    const int llo = lane & 15;
    float vout[4][4][4];
    float psum[4] = {0.f, 0.f, 0.f, 0.f};
    float psq[4]  = {0.f, 0.f, 0.f, 0.f};
#pragma unroll
    for (int m = 0; m < 4; ++m) {
        const int f0 = wid * 64 + m * 16 + (lhi << 2);
        const float4 bia = *(const float4*)&bcomb[f0];
#pragma unroll
        for (int n = 0; n < 4; ++n) {
            const float v0 = acc[m][n][0] + bia.x;
            const float v1 = acc[m][n][1] + bia.y;
            const float v2 = acc[m][n][2] + bia.z;
            const float v3 = acc[m][n][3] + bia.w;
            vout[m][n][0] = v0; vout[m][n][1] = v1;
            vout[m][n][2] = v2; vout[m][n][3] = v3;
            psum[n] += v0 + v1 + v2 + v3;
            psq[n]  += v0 * v0 + v1 * v1 + v2 * v2 + v3 * v3;
        }
    }
#pragma unroll
    for (int n = 0; n < 4; ++n) {
        psum[n] += __shfl_xor(psum[n], 16);
        psum[n] += __shfl_xor(psum[n], 32);
        psq[n]  += __shfl_xor(psq[n], 16);
        psq[n]  += __shfl_xor(psq[n], 32);
    }
    if (lhi == 0) {
#pragma unroll
        for (int n = 0; n < 4; ++n) {
            redS[wid][n * 16 + llo] = psum[n];
            redQ[wid][n * 16 + llo] = psq[n];
        }
    }
    __syncthreads();
    float mean[4], inv[4];
#pragma unroll
    for (int n = 0; n < 4; ++n) {
        const int nd = n * 16 + llo;
        const float S = redS[0][nd] + redS[1][nd] + redS[2][nd] + redS[3][nd];
        const float Q = redQ[0][nd] + redQ[1][nd] + redQ[2][nd] + redQ[3][nd];
        const float mu = S * (1.0f / DIM);
        const float var = Q * (1.0f / DIM) - mu * mu;
        mean[n] = mu;
        inv[n] = 1.0f / sqrtf(var + 1e-5f);
    }
#pragma unroll
    for (int m = 0; m < 4; ++m) {
        const int f0 = wid * 64 + m * 16 + (lhi << 2);
        const float4 gv = *(const float4*)&gamma[f0];
        const float4 bv = *(const float4*)&beta[f0];
#pragma unroll
        for (int n = 0; n < 4; ++n) {
            const int node = ndB + n * 16 + llo;
            float4 r;
            r.x = (vout[m][n][0] - mean[n]) * inv[n] * gv.x + bv.x;
            r.y = (vout[m][n][1] - mean[n]) * inv[n] * gv.y + bv.y;
            r.z = (vout[m][n][2] - mean[n]) * inv[n] * gv.z + bv.z;
            r.w = (vout[m][n][3] - mean[n]) * inv[n] * gv.w + bv.w;
            *(float4*)&out[(size_t)node * DIM + f0] = r;
        }
    }
}

// ---------------------------------------------------------------- sparse attention
// XCD-pinned per-head partition (FETCH 364->37MB); atomic-free popcount+scan decode
// (conflicts 901K->19K); 4-neighbor subgroup gather (110->62us). Only change:
// output written node-major [node][h*256+d] to feed the merged projection.
__global__ __launch_bounds__(256) void attn_sparse_kernel(const unsigned* __restrict__ mask,
                                                          const ushort_t* __restrict__ qb,
                                                          const ushort_t* __restrict__ kvh,
                                                          ushort_t* __restrict__ ob) {
    __shared__ int nbr[4][MAXDEG];
    const int tid = threadIdx.x;
    const int w = tid >> 6;
    const int lane = tid & 63;
    const int xcd = blockIdx.x & 7;
    const int h = xcd >> 1;
    const int node = ((xcd & 1) << 11) + ((blockIdx.x >> 3) << 2) + w;

    const unsigned m0 = mask[node * MWORDS + lane];
    const unsigned m1 = mask[node * MWORDS + 64 + lane];
    const int c = __popc(m0) + __popc(m1);
    int s = c;
#pragma unroll
    for (int d = 1; d < 64; d <<= 1) {
        const int t = __shfl_up(s, d);
        if (lane >= d) s += t;
    }
    const int deg0 = __shfl(s, 63);
    const int deg = deg0 < MAXDEG ? deg0 : MAXDEG;
    int pos = s - c;
    unsigned mm = m0;
    int bj = lane << 5;
    while (mm) {
        const int b = __ffs(mm) - 1; mm &= mm - 1;
        if (pos < MAXDEG) nbr[w][pos] = bj + b;
        ++pos;
    }
    mm = m1; bj = (lane + 64) << 5;
    while (mm) {
        const int b = __ffs(mm) - 1; mm &= mm - 1;
        if (pos < MAXDEG) nbr[w][pos] = bj + b;
        ++pos;
    }
    __syncthreads();

    const int sub = lane >> 4;
    const int sl = lane & 15;

    const ushort_t* qp = qb + (((size_t)h * N_NODES + node) << 8) + (sl << 4);
    const short8 q0 = *(const short8*)qp;
    const short8 q1 = *(const short8*)(qp + 8);
    float qf[16];
#pragma unroll
    for (int i = 0; i < 8; ++i) {
        qf[i] = bf2f((ushort_t)q0[i]);
        qf[8 + i] = bf2f((ushort_t)q1[i]);
    }
    float oa[16];
#pragma unroll
    for (int i = 0; i < 16; ++i) oa[i] = 0.f;
    float denom = 0.f;

    const ushort_t* kbase = kvh + (((size_t)h * N_NODES) << 9) + (sl << 4);
    const float SC = 0.0625f * 1.44269504f;   // 1/sqrt(256) * log2(e)

    for (int n0 = 0; n0 < deg; n0 += 4) {
        const int idx = n0 + sub;
        const bool valid = idx < deg;
        const int j = nbr[w][valid ? idx : 0];
        const ushort_t* kp = kbase + ((size_t)j << 9);
        const short8 k0 = *(const short8*)kp;
        const short8 k1 = *(const short8*)(kp + 8);
        const short8 v0 = *(const short8*)(kp + 256);
        const short8 v1 = *(const short8*)(kp + 264);
        float p = 0.f;
#pragma unroll
        for (int i = 0; i < 8; ++i)
            p += qf[i] * bf2f((ushort_t)k0[i]) + qf[8 + i] * bf2f((ushort_t)k1[i]);
        p += __shfl_xor(p, 1);
        p += __shfl_xor(p, 2);
        p += __shfl_xor(p, 4);
        p += __shfl_xor(p, 8);
        const float wt = valid ? __builtin_amdgcn_exp2f(p * SC) : 0.f;
        denom += wt;
#pragma unroll
        for (int i = 0; i < 8; ++i) {
            oa[i] += wt * bf2f((ushort_t)v0[i]);
            oa[8 + i] += wt * bf2f((ushort_t)v1[i]);
        }
    }
    denom += __shfl_xor(denom, 16);
    denom += __shfl_xor(denom, 32);
#pragma unroll
    for (int i = 0; i < 16; ++i) {
        oa[i] += __shfl_xor(oa[i], 16);
        oa[i] += __shfl_xor(oa[i], 32);
    }
    if (sub == 0) {
        const float inv = 1.0f / denom;
        short8 r0, r1;
#pragma unroll
        for (int i = 0; i < 8; ++i) {
            r0[i] = (short)f2bf(oa[i] * inv);
            r1[i] = (short)f2bf(oa[8 + i] * inv);
        }
        ushort_t* op_ = ob + (size_t)node * 1024 + (h << 8) + (sl << 4);
        *(short8*)op_ = r0;
        *(short8*)(op_ + 8) = r1;
    }
}

// ---------------------------------------------------------------- launcher
extern "C" void kernel_launch(void* const* d_in, const int* in_sizes, int n_in,
                              void* d_out, int out_size, void* d_ws, size_t ws_size,
                              hipStream_t stream) {
    const float* x     = (const float*)d_in[0];
    const int*   ei    = (const int*)d_in[1];
    const float* Wq    = (const float*)d_in[2];
    const float* bq    = (const float*)d_in[3];
    const float* Wk    = (const float*)d_in[4];
    const float* bk    = (const float*)d_in[5];
    const float* Wv    = (const float*)d_in[6];
    const float* bv    = (const float*)d_in[7];
    const float* Wo    = (const float*)d_in[8];
    const float* bo    = (const float*)d_in[9];
    const float* Wp    = (const float*)d_in[10];
    const float* bp    = (const float*)d_in[11];
    const float* gamma = (const float*)d_in[12];
    const float* beta  = (const float*)d_in[13];
    float* outf = (float*)d_out;

    char* ws = (char*)d_ws;
    unsigned* mask   = (unsigned*)(ws);                           // 2 MB
    float*    bcomb  = (float*)   (ws + (size_t)( 2 << 20));      // 1 KB (zeroed)
    ushort_t* xb     = (ushort_t*)(ws + (size_t)( 4 << 20));      // 2 MB  bf16 [4096][256]
    ushort_t* qb     = (ushort_t*)(ws + (size_t)( 6 << 20));      // 8 MB  bf16 [h][n][256]
    ushort_t* kvh    = (ushort_t*)(ws + (size_t)(14 << 20));      // 16 MB bf16 [h][n][512]
    ushort_t* ob     = (ushort_t*)(ws + (size_t)(30 << 20));      // 8 MB  bf16 [n][1024] node-major
    ushort_t* wstack = (ushort_t*)(ws + (size_t)(48 << 20));      // 1.5 MB bf16 [3072][256]
    ushort_t* mstack = (ushort_t*)(ws + (size_t)(50 << 20));      // 0.5 MB bf16 [256][1024]

    hipMemsetAsync(ws, 0, (size_t)(2 << 20) + 1024, stream);      // mask + bcomb

    init_kernel<<<MASK_BLOCKS + CONV_BLOCKS + PREP_BLOCKS, 256, 0, stream>>>(
        ei, mask, x, Wq, Wk, Wv, Wo, Wp, bo, bp, xb, wstack, mstack, bcomb);

    // QKV: 3072 channels x 4096 nodes, K=256
    qkv_gemm_kernel<<<dim3(24, 32), 256, 0, stream>>>(wstack, xb, bq, bk, bv, qb, kvh);

    attn_sparse_kernel<<<N_NODES, 256, 0, stream>>>(mask, qb, kvh, ob);

    // merged out-proj + final-proj + LayerNorm: K=1024, 64 blocks of 256f x 64n
    final_ln_kernel<<<64, 256, 0, stream>>>(mstack, ob, bcomb, gamma, beta, outf);
}